// Round 1
// baseline (444.915 us; speedup 1.0000x reference)
//
#include <hip/hip_runtime.h>

#define DFEAT 64

// Stage 2: degree count via float atomics.
__global__ void gcn_deg_kernel(const int* __restrict__ row,
                               float* __restrict__ deg, int E) {
    int e = blockIdx.x * blockDim.x + threadIdx.x;
    if (e < E) atomicAdd(&deg[row[e]], 1.0f);
}

// Stage 3: deg -> d^{-1/2} in place.
__global__ void gcn_rsqrt_kernel(float* __restrict__ deg, int N) {
    int i = blockIdx.x * blockDim.x + threadIdx.x;
    if (i < N) {
        float d = deg[i];
        deg[i] = (d > 0.0f) ? rsqrtf(d) : 0.0f;
    }
}

// Stage 4: one wave (64 lanes) per edge; lane = feature dim.
// row/col/dinv loads are wave-uniform; feat read and out atomic are
// coalesced 256B bursts.
__global__ void gcn_scatter_kernel(const int* __restrict__ row,
                                   const int* __restrict__ col,
                                   const float* __restrict__ feat,
                                   const float* __restrict__ dinv,
                                   float* __restrict__ out, int E) {
    long long tid = (long long)blockIdx.x * blockDim.x + threadIdx.x;
    int e = (int)(tid >> 6);
    int d = (int)(tid & 63);
    if (e < E) {
        int r = row[e];
        int c = col[e];
        float v = dinv[r] * dinv[c];
        float x = feat[(long long)c * DFEAT + d];
        atomicAdd(&out[(long long)r * DFEAT + d], v * x);
    }
}

extern "C" void kernel_launch(void* const* d_in, const int* in_sizes, int n_in,
                              void* d_out, int out_size, void* d_ws, size_t ws_size,
                              hipStream_t stream) {
    const float* feat = (const float*)d_in[0];
    const int*   row  = (const int*)d_in[1];
    const int*   col  = (const int*)d_in[2];
    float* out = (float*)d_out;

    int N = in_sizes[0] / DFEAT;   // 100000
    int E = in_sizes[1];           // 1600000

    float* deg = (float*)d_ws;     // N floats of scratch

    hipMemsetAsync(out, 0, (size_t)out_size * sizeof(float), stream);
    hipMemsetAsync(deg, 0, (size_t)N * sizeof(float), stream);

    gcn_deg_kernel<<<(E + 255) / 256, 256, 0, stream>>>(row, deg, E);
    gcn_rsqrt_kernel<<<(N + 255) / 256, 256, 0, stream>>>(deg, N);

    long long total = (long long)E * DFEAT;
    int blocks = (int)((total + 255) / 256);
    gcn_scatter_kernel<<<blocks, 256, 0, stream>>>(row, col, feat, deg, out, E);
}

// Round 2
// 355.556 us; speedup vs baseline: 1.2513x; 1.2513x over previous
//
#include <hip/hip_runtime.h>

#define DFEAT 64
#define SCAN_B 1024

// ---------- CSR-build path ----------

__global__ void gcn_hist_kernel(const int* __restrict__ row,
                                unsigned* __restrict__ cnt, int E) {
    int e = blockIdx.x * blockDim.x + threadIdx.x;
    if (e < E) atomicAdd(&cnt[row[e]], 1u);
}

__global__ void gcn_dinv_kernel(const unsigned* __restrict__ cnt,
                                float* __restrict__ dinv, int N) {
    int i = blockIdx.x * blockDim.x + threadIdx.x;
    if (i < N) {
        unsigned d = cnt[i];
        dinv[i] = d ? rsqrtf((float)d) : 0.0f;
    }
}

// Per-block exclusive scan (Hillis-Steele in LDS); block totals to bsum.
__global__ void gcn_scan_block_kernel(const unsigned* __restrict__ in,
                                      unsigned* __restrict__ part,
                                      unsigned* __restrict__ bsum, int n) {
    __shared__ unsigned tmp[SCAN_B];
    int tid = threadIdx.x;
    int i = blockIdx.x * SCAN_B + tid;
    unsigned v = (i < n) ? in[i] : 0u;
    tmp[tid] = v;
    __syncthreads();
    for (int off = 1; off < SCAN_B; off <<= 1) {
        unsigned t = (tid >= off) ? tmp[tid - off] : 0u;
        __syncthreads();
        tmp[tid] += t;
        __syncthreads();
    }
    if (i < n) part[i] = tmp[tid] - v;       // exclusive
    if (tid == 0) bsum[blockIdx.x] = tmp[SCAN_B - 1];
}

// Add scanned block offsets; produce row_ptr and a fill copy for scatter.
__global__ void gcn_scan_fixup_kernel(const unsigned* __restrict__ part,
                                      const unsigned* __restrict__ bscan,
                                      unsigned* __restrict__ row_ptr,
                                      unsigned* __restrict__ fill,
                                      int n, int E) {
    int i = blockIdx.x * blockDim.x + threadIdx.x;
    if (i < n) {
        unsigned v = part[i] + bscan[i / SCAN_B];
        row_ptr[i] = v;
        fill[i] = v;
    }
    if (i == 0) row_ptr[n] = (unsigned)E;
}

__global__ void gcn_csr_scatter_kernel(const int* __restrict__ row,
                                       const int* __restrict__ col,
                                       unsigned* __restrict__ fill,
                                       int* __restrict__ col_sorted, int E) {
    int e = blockIdx.x * blockDim.x + threadIdx.x;
    if (e < E) {
        unsigned pos = atomicAdd(&fill[row[e]], 1u);
        col_sorted[pos] = col[e];
    }
}

// One wave per node; lane = feature dim. No output atomics.
__global__ void gcn_gather_kernel(const unsigned* __restrict__ row_ptr,
                                  const int* __restrict__ col_sorted,
                                  const float* __restrict__ feat,
                                  const float* __restrict__ dinv,
                                  float* __restrict__ out, int N) {
    int node = blockIdx.x * 4 + (threadIdx.x >> 6);
    int lane = threadIdx.x & 63;
    if (node >= N) return;
    unsigned s = row_ptr[node];
    unsigned epos = row_ptr[node + 1];
    float acc = 0.0f;
    for (unsigned j = s; j < epos; ++j) {
        int c = col_sorted[j];
        acc += dinv[c] * feat[(long long)c * DFEAT + lane];
    }
    out[(long long)node * DFEAT + lane] = dinv[node] * acc;
}

// ---------- fallback (round-1 atomic path) ----------

__global__ void gcn_deg_kernel(const int* __restrict__ row,
                               float* __restrict__ deg, int E) {
    int e = blockIdx.x * blockDim.x + threadIdx.x;
    if (e < E) atomicAdd(&deg[row[e]], 1.0f);
}

__global__ void gcn_rsqrt_kernel(float* __restrict__ deg, int N) {
    int i = blockIdx.x * blockDim.x + threadIdx.x;
    if (i < N) {
        float d = deg[i];
        deg[i] = (d > 0.0f) ? rsqrtf(d) : 0.0f;
    }
}

__global__ void gcn_scatter_kernel(const int* __restrict__ row,
                                   const int* __restrict__ col,
                                   const float* __restrict__ feat,
                                   const float* __restrict__ dinv,
                                   float* __restrict__ out, int E) {
    long long tid = (long long)blockIdx.x * blockDim.x + threadIdx.x;
    int e = (int)(tid >> 6);
    int d = (int)(tid & 63);
    if (e < E) {
        int r = row[e];
        int c = col[e];
        float v = dinv[r] * dinv[c];
        float x = feat[(long long)c * DFEAT + d];
        atomicAdd(&out[(long long)r * DFEAT + d], v * x);
    }
}

extern "C" void kernel_launch(void* const* d_in, const int* in_sizes, int n_in,
                              void* d_out, int out_size, void* d_ws, size_t ws_size,
                              hipStream_t stream) {
    const float* feat = (const float*)d_in[0];
    const int*   row  = (const int*)d_in[1];
    const int*   col  = (const int*)d_in[2];
    float* out = (float*)d_out;

    int N = in_sizes[0] / DFEAT;   // 100000
    int E = in_sizes[1];           // 1600000
    int NB = (N + SCAN_B - 1) / SCAN_B;

    // ws layout (4-byte units)
    size_t need = (size_t)(5 * N + 2 + 2 * NB + 2) * 4 + (size_t)E * 4;
    if (ws_size < need) {
        // fallback: atomic scatter path
        float* deg = (float*)d_ws;
        hipMemsetAsync(out, 0, (size_t)out_size * sizeof(float), stream);
        hipMemsetAsync(deg, 0, (size_t)N * sizeof(float), stream);
        gcn_deg_kernel<<<(E + 255) / 256, 256, 0, stream>>>(row, deg, E);
        gcn_rsqrt_kernel<<<(N + 255) / 256, 256, 0, stream>>>(deg, N);
        long long total = (long long)E * DFEAT;
        gcn_scatter_kernel<<<(int)((total + 255) / 256), 256, 0, stream>>>(
            row, col, feat, deg, out, E);
        return;
    }

    unsigned* cnt      = (unsigned*)d_ws;           // N
    unsigned* part     = cnt + N;                   // N
    unsigned* row_ptr  = part + N;                  // N+1
    unsigned* fill     = row_ptr + N + 1;           // N
    unsigned* bsum     = fill + N;                  // NB
    unsigned* bscan    = bsum + NB;                 // NB
    unsigned* bscratch = bscan + NB;                // 1 (dummy total)
    float*    dinv     = (float*)(bscratch + 1);    // N
    int*      col_sorted = (int*)(dinv + N);        // E

    hipMemsetAsync(cnt, 0, (size_t)N * sizeof(unsigned), stream);

    gcn_hist_kernel<<<(E + 255) / 256, 256, 0, stream>>>(row, cnt, E);
    gcn_dinv_kernel<<<(N + 255) / 256, 256, 0, stream>>>(cnt, dinv, N);
    gcn_scan_block_kernel<<<NB, SCAN_B, 0, stream>>>(cnt, part, bsum, N);
    gcn_scan_block_kernel<<<1, SCAN_B, 0, stream>>>(bsum, bscan, bscratch, NB);
    gcn_scan_fixup_kernel<<<(N + 255) / 256, 256, 0, stream>>>(part, bscan,
                                                               row_ptr, fill, N, E);
    gcn_csr_scatter_kernel<<<(E + 255) / 256, 256, 0, stream>>>(row, col, fill,
                                                                col_sorted, E);
    gcn_gather_kernel<<<(N + 3) / 4, 256, 0, stream>>>(row_ptr, col_sorted,
                                                       feat, dinv, out, N);
}

// Round 3
// 266.634 us; speedup vs baseline: 1.6686x; 1.3335x over previous
//
#include <hip/hip_runtime.h>

#define DFEAT 64
#define SCAN_B 1024

// ---------- CSR-build path ----------

// 4 edges per thread via int4.
__global__ void gcn_hist_kernel(const int* __restrict__ row,
                                unsigned* __restrict__ cnt, int E) {
    int t = blockIdx.x * blockDim.x + threadIdx.x;
    int e = t * 4;
    if (e + 3 < E) {
        int4 r = *(const int4*)(row + e);
        atomicAdd(&cnt[r.x], 1u);
        atomicAdd(&cnt[r.y], 1u);
        atomicAdd(&cnt[r.z], 1u);
        atomicAdd(&cnt[r.w], 1u);
    } else {
        for (; e < E; ++e) atomicAdd(&cnt[row[e]], 1u);
    }
}

// Per-block exclusive scan (Hillis-Steele in LDS); block totals to bsum.
__global__ void gcn_scan_block_kernel(const unsigned* __restrict__ in,
                                      unsigned* __restrict__ part,
                                      unsigned* __restrict__ bsum, int n) {
    __shared__ unsigned tmp[SCAN_B];
    int tid = threadIdx.x;
    int i = blockIdx.x * SCAN_B + tid;
    unsigned v = (i < n) ? in[i] : 0u;
    tmp[tid] = v;
    __syncthreads();
    for (int off = 1; off < SCAN_B; off <<= 1) {
        unsigned t = (tid >= off) ? tmp[tid - off] : 0u;
        __syncthreads();
        tmp[tid] += t;
        __syncthreads();
    }
    if (i < n) part[i] = tmp[tid] - v;       // exclusive
    if (tid == 0) bsum[blockIdx.x] = tmp[SCAN_B - 1];
}

// Add scanned block offsets; produce row_ptr, fill copy, and dinv (fused).
__global__ void gcn_scan_fixup_kernel(const unsigned* __restrict__ part,
                                      const unsigned* __restrict__ bscan,
                                      const unsigned* __restrict__ cnt,
                                      unsigned* __restrict__ row_ptr,
                                      unsigned* __restrict__ fill,
                                      float* __restrict__ dinv,
                                      int n, int E) {
    int i = blockIdx.x * blockDim.x + threadIdx.x;
    if (i < n) {
        unsigned v = part[i] + bscan[i / SCAN_B];
        row_ptr[i] = v;
        fill[i] = v;
        unsigned d = cnt[i];
        dinv[i] = d ? rsqrtf((float)d) : 0.0f;
    }
    if (i == 0) row_ptr[n] = (unsigned)E;
}

__global__ void gcn_csr_scatter_kernel(const int* __restrict__ row,
                                       const int* __restrict__ col,
                                       unsigned* __restrict__ fill,
                                       int* __restrict__ col_sorted, int E) {
    int e = blockIdx.x * blockDim.x + threadIdx.x;
    if (e < E) {
        unsigned pos = atomicAdd(&fill[row[e]], 1u);
        col_sorted[pos] = col[e];
    }
}

// One wave per node; 4 edge-groups x 16 lanes, float4 feature loads,
// 2x unroll -> up to 8 feature rows in flight per wave.
__global__ __launch_bounds__(256) void gcn_gather_kernel(
    const unsigned* __restrict__ row_ptr,
    const int* __restrict__ col_sorted,
    const float* __restrict__ feat,
    const float* __restrict__ dinv,
    float* __restrict__ out, int N) {
    int node = blockIdx.x * 4 + (threadIdx.x >> 6);
    if (node >= N) return;
    int lane = threadIdx.x & 63;
    int grp = lane >> 4;       // 0..3: edge group
    int sub = lane & 15;       // 0..15: float4 slot within feature row

    unsigned s = row_ptr[node];
    unsigned epos = row_ptr[node + 1];

    float4 acc = make_float4(0.f, 0.f, 0.f, 0.f);
    unsigned j = s + grp;
    // 2x unroll: two independent edges in flight per group.
    for (; j + 4 < epos; j += 8) {
        int c0 = col_sorted[j];
        int c1 = col_sorted[j + 4];
        float w0 = dinv[c0];
        float w1 = dinv[c1];
        float4 x0 = ((const float4*)(feat + (size_t)c0 * DFEAT))[sub];
        float4 x1 = ((const float4*)(feat + (size_t)c1 * DFEAT))[sub];
        acc.x += w0 * x0.x + w1 * x1.x;
        acc.y += w0 * x0.y + w1 * x1.y;
        acc.z += w0 * x0.z + w1 * x1.z;
        acc.w += w0 * x0.w + w1 * x1.w;
    }
    if (j < epos) {
        int c0 = col_sorted[j];
        float w0 = dinv[c0];
        float4 x0 = ((const float4*)(feat + (size_t)c0 * DFEAT))[sub];
        acc.x += w0 * x0.x;
        acc.y += w0 * x0.y;
        acc.z += w0 * x0.z;
        acc.w += w0 * x0.w;
    }
    // Reduce the 4 groups: lanes l, l+16, l+32, l+48 hold partials for
    // the same feature slots.
    acc.x += __shfl_xor(acc.x, 16, 64);
    acc.y += __shfl_xor(acc.y, 16, 64);
    acc.z += __shfl_xor(acc.z, 16, 64);
    acc.w += __shfl_xor(acc.w, 16, 64);
    acc.x += __shfl_xor(acc.x, 32, 64);
    acc.y += __shfl_xor(acc.y, 32, 64);
    acc.z += __shfl_xor(acc.z, 32, 64);
    acc.w += __shfl_xor(acc.w, 32, 64);

    if (grp == 0) {
        float w = dinv[node];
        float4 o = make_float4(w * acc.x, w * acc.y, w * acc.z, w * acc.w);
        ((float4*)(out + (size_t)node * DFEAT))[sub] = o;
    }
}

// ---------- fallback (round-1 atomic path) ----------

__global__ void gcn_deg_kernel(const int* __restrict__ row,
                               float* __restrict__ deg, int E) {
    int e = blockIdx.x * blockDim.x + threadIdx.x;
    if (e < E) atomicAdd(&deg[row[e]], 1.0f);
}

__global__ void gcn_rsqrt_kernel(float* __restrict__ deg, int N) {
    int i = blockIdx.x * blockDim.x + threadIdx.x;
    if (i < N) {
        float d = deg[i];
        deg[i] = (d > 0.0f) ? rsqrtf(d) : 0.0f;
    }
}

__global__ void gcn_scatter_kernel(const int* __restrict__ row,
                                   const int* __restrict__ col,
                                   const float* __restrict__ feat,
                                   const float* __restrict__ dinv,
                                   float* __restrict__ out, int E) {
    long long tid = (long long)blockIdx.x * blockDim.x + threadIdx.x;
    int e = (int)(tid >> 6);
    int d = (int)(tid & 63);
    if (e < E) {
        int r = row[e];
        int c = col[e];
        float v = dinv[r] * dinv[c];
        float x = feat[(long long)c * DFEAT + d];
        atomicAdd(&out[(long long)r * DFEAT + d], v * x);
    }
}

extern "C" void kernel_launch(void* const* d_in, const int* in_sizes, int n_in,
                              void* d_out, int out_size, void* d_ws, size_t ws_size,
                              hipStream_t stream) {
    const float* feat = (const float*)d_in[0];
    const int*   row  = (const int*)d_in[1];
    const int*   col  = (const int*)d_in[2];
    float* out = (float*)d_out;

    int N = in_sizes[0] / DFEAT;   // 100000
    int E = in_sizes[1];           // 1600000
    int NB = (N + SCAN_B - 1) / SCAN_B;

    size_t need = (size_t)(5 * N + 2 + 2 * NB + 2) * 4 + (size_t)E * 4;
    if (ws_size < need) {
        float* deg = (float*)d_ws;
        hipMemsetAsync(out, 0, (size_t)out_size * sizeof(float), stream);
        hipMemsetAsync(deg, 0, (size_t)N * sizeof(float), stream);
        gcn_deg_kernel<<<(E + 255) / 256, 256, 0, stream>>>(row, deg, E);
        gcn_rsqrt_kernel<<<(N + 255) / 256, 256, 0, stream>>>(deg, N);
        long long total = (long long)E * DFEAT;
        gcn_scatter_kernel<<<(int)((total + 255) / 256), 256, 0, stream>>>(
            row, col, feat, deg, out, E);
        return;
    }

    unsigned* cnt      = (unsigned*)d_ws;           // N
    unsigned* part     = cnt + N;                   // N
    unsigned* row_ptr  = part + N;                  // N+1
    unsigned* fill     = row_ptr + N + 1;           // N
    unsigned* bsum     = fill + N;                  // NB
    unsigned* bscan    = bsum + NB;                 // NB
    unsigned* bscratch = bscan + NB;                // 1
    float*    dinv     = (float*)(bscratch + 1);    // N
    int*      col_sorted = (int*)(dinv + N);        // E

    hipMemsetAsync(cnt, 0, (size_t)N * sizeof(unsigned), stream);

    int histThreads = (E + 3) / 4;
    gcn_hist_kernel<<<(histThreads + 255) / 256, 256, 0, stream>>>(row, cnt, E);
    gcn_scan_block_kernel<<<NB, SCAN_B, 0, stream>>>(cnt, part, bsum, N);
    gcn_scan_block_kernel<<<1, SCAN_B, 0, stream>>>(bsum, bscan, bscratch, NB);
    gcn_scan_fixup_kernel<<<(N + 255) / 256, 256, 0, stream>>>(
        part, bscan, cnt, row_ptr, fill, dinv, N, E);
    gcn_csr_scatter_kernel<<<(E + 255) / 256, 256, 0, stream>>>(row, col, fill,
                                                                col_sorted, E);
    gcn_gather_kernel<<<(N + 3) / 4, 256, 0, stream>>>(row_ptr, col_sorted,
                                                       feat, dinv, out, N);
}

// Round 4
// 198.735 us; speedup vs baseline: 2.2387x; 1.3417x over previous
//
#include <hip/hip_runtime.h>

#define DFEAT 64
#define SCAN_B 1024
#define RPB 128            // rows per bucket (power of 2)
#define RPB_SHIFT 7
#define KMAX 800           // LDS sizing for bin kernel (K = ceil(N/RPB))
#define BIN_CHUNK 16384

// ---------- CSR-build path ----------

// 4 edges per thread via int4.
__global__ void gcn_hist_kernel(const int* __restrict__ row,
                                unsigned* __restrict__ cnt, int E) {
    int t = blockIdx.x * blockDim.x + threadIdx.x;
    int e = t * 4;
    if (e + 3 < E) {
        int4 r = *(const int4*)(row + e);
        atomicAdd(&cnt[r.x], 1u);
        atomicAdd(&cnt[r.y], 1u);
        atomicAdd(&cnt[r.z], 1u);
        atomicAdd(&cnt[r.w], 1u);
    } else {
        for (; e < E; ++e) atomicAdd(&cnt[row[e]], 1u);
    }
}

// Per-block exclusive scan (Hillis-Steele in LDS); block totals to bsum.
__global__ void gcn_scan_block_kernel(const unsigned* __restrict__ in,
                                      unsigned* __restrict__ part,
                                      unsigned* __restrict__ bsum, int n) {
    __shared__ unsigned tmp[SCAN_B];
    int tid = threadIdx.x;
    int i = blockIdx.x * SCAN_B + tid;
    unsigned v = (i < n) ? in[i] : 0u;
    tmp[tid] = v;
    __syncthreads();
    for (int off = 1; off < SCAN_B; off <<= 1) {
        unsigned t = (tid >= off) ? tmp[tid - off] : 0u;
        __syncthreads();
        tmp[tid] += t;
        __syncthreads();
    }
    if (i < n) part[i] = tmp[tid] - v;       // exclusive
    if (tid == 0) bsum[blockIdx.x] = tmp[SCAN_B - 1];
}

// Add scanned block offsets; produce row_ptr, fill copy, and dinv (fused).
__global__ void gcn_scan_fixup_kernel(const unsigned* __restrict__ part,
                                      const unsigned* __restrict__ bscan,
                                      const unsigned* __restrict__ cnt,
                                      unsigned* __restrict__ row_ptr,
                                      unsigned* __restrict__ fill,
                                      float* __restrict__ dinv,
                                      int n, int E) {
    int i = blockIdx.x * blockDim.x + threadIdx.x;
    if (i < n) {
        unsigned v = part[i] + bscan[i / SCAN_B];
        row_ptr[i] = v;
        fill[i] = v;
        unsigned d = cnt[i];
        dinv[i] = d ? rsqrtf((float)d) : 0.0f;
    }
    if (i == 0) row_ptr[n] = (unsigned)E;
}

// Bucketed bin: LDS-aggregated per-bucket counts, one global reservation per
// (block,bucket), packed 4B writes in contiguous per-block runs.
__global__ __launch_bounds__(256) void gcn_bin_kernel(
    const int* __restrict__ row, const int* __restrict__ col,
    const unsigned* __restrict__ row_ptr,
    unsigned* __restrict__ bucket_fill,   // K counters, zeroed
    int* __restrict__ pair_buf,           // E packed words (lives in d_out)
    int E, int N, int K) {
    __shared__ unsigned cnt[KMAX];
    __shared__ unsigned res[KMAX];
    __shared__ unsigned wcnt[KMAX];
    __shared__ unsigned base[KMAX];
    int tid = threadIdx.x;
    long long e0 = (long long)blockIdx.x * BIN_CHUNK;
    int nE = min(BIN_CHUNK, (int)(E - e0));

    for (int k = tid; k < K; k += 256) { cnt[k] = 0u; wcnt[k] = 0u; }
    __syncthreads();

    for (int i = tid; i < nE; i += 256) {
        int r = row[e0 + i];
        atomicAdd(&cnt[r >> RPB_SHIFT], 1u);
    }
    __syncthreads();

    for (int k = tid; k < K; k += 256) {
        unsigned c = cnt[k];
        res[k] = c ? atomicAdd(&bucket_fill[k], c) : 0u;
        base[k] = row_ptr[k << RPB_SHIFT];
    }
    __syncthreads();

    for (int i = tid; i < nE; i += 256) {
        int r = row[e0 + i];
        int c = col[e0 + i];
        int k = r >> RPB_SHIFT;
        unsigned rank = atomicAdd(&wcnt[k], 1u);
        pair_buf[base[k] + res[k] + rank] = ((r & (RPB - 1)) << 17) | c;
    }
}

// One block per bucket: rank edges per row in LDS, write col_sorted into the
// bucket-local CSR region (single-XCD locality, full-line writebacks).
__global__ __launch_bounds__(256) void gcn_rank_kernel(
    const int* __restrict__ pair_buf,
    const unsigned* __restrict__ row_ptr,
    int* __restrict__ col_sorted, int N) {
    int k = blockIdx.x;
    int row0 = k << RPB_SHIFT;
    int rows_in = min(RPB, N - row0);
    __shared__ unsigned rp[RPB + 1];
    __shared__ unsigned fillc[RPB];
    int tid = threadIdx.x;
    if (tid <= rows_in) rp[tid] = row_ptr[row0 + tid];
    if (tid < rows_in) fillc[tid] = 0u;
    __syncthreads();
    unsigned base = rp[0];
    unsigned size = rp[rows_in] - base;
    for (unsigned i = tid; i < size; i += 256) {
        int w = pair_buf[base + i];
        int lr = w >> 17;
        int c = w & 0x1FFFF;
        unsigned rank = atomicAdd(&fillc[lr], 1u);
        col_sorted[rp[lr] + rank] = c;
    }
}

// Fallback CSR scatter (used only if K > KMAX).
__global__ void gcn_csr_scatter_kernel(const int* __restrict__ row,
                                       const int* __restrict__ col,
                                       unsigned* __restrict__ fill,
                                       int* __restrict__ col_sorted, int E) {
    int e = blockIdx.x * blockDim.x + threadIdx.x;
    if (e < E) {
        unsigned pos = atomicAdd(&fill[row[e]], 1u);
        col_sorted[pos] = col[e];
    }
}

// One wave per node; 4 edge-groups x 16 lanes, float4 feature loads,
// 2x unroll -> up to 8 feature rows in flight per wave.
__global__ __launch_bounds__(256) void gcn_gather_kernel(
    const unsigned* __restrict__ row_ptr,
    const int* __restrict__ col_sorted,
    const float* __restrict__ feat,
    const float* __restrict__ dinv,
    float* __restrict__ out, int N) {
    int node = blockIdx.x * 4 + (threadIdx.x >> 6);
    if (node >= N) return;
    int lane = threadIdx.x & 63;
    int grp = lane >> 4;
    int sub = lane & 15;

    unsigned s = row_ptr[node];
    unsigned epos = row_ptr[node + 1];

    float4 acc = make_float4(0.f, 0.f, 0.f, 0.f);
    unsigned j = s + grp;
    for (; j + 4 < epos; j += 8) {
        int c0 = col_sorted[j];
        int c1 = col_sorted[j + 4];
        float w0 = dinv[c0];
        float w1 = dinv[c1];
        float4 x0 = ((const float4*)(feat + (size_t)c0 * DFEAT))[sub];
        float4 x1 = ((const float4*)(feat + (size_t)c1 * DFEAT))[sub];
        acc.x += w0 * x0.x + w1 * x1.x;
        acc.y += w0 * x0.y + w1 * x1.y;
        acc.z += w0 * x0.z + w1 * x1.z;
        acc.w += w0 * x0.w + w1 * x1.w;
    }
    if (j < epos) {
        int c0 = col_sorted[j];
        float w0 = dinv[c0];
        float4 x0 = ((const float4*)(feat + (size_t)c0 * DFEAT))[sub];
        acc.x += w0 * x0.x;
        acc.y += w0 * x0.y;
        acc.z += w0 * x0.z;
        acc.w += w0 * x0.w;
    }
    acc.x += __shfl_xor(acc.x, 16, 64);
    acc.y += __shfl_xor(acc.y, 16, 64);
    acc.z += __shfl_xor(acc.z, 16, 64);
    acc.w += __shfl_xor(acc.w, 16, 64);
    acc.x += __shfl_xor(acc.x, 32, 64);
    acc.y += __shfl_xor(acc.y, 32, 64);
    acc.z += __shfl_xor(acc.z, 32, 64);
    acc.w += __shfl_xor(acc.w, 32, 64);

    if (grp == 0) {
        float w = dinv[node];
        float4 o = make_float4(w * acc.x, w * acc.y, w * acc.z, w * acc.w);
        ((float4*)(out + (size_t)node * DFEAT))[sub] = o;
    }
}

// ---------- fallback (round-1 atomic path) ----------

__global__ void gcn_deg_kernel(const int* __restrict__ row,
                               float* __restrict__ deg, int E) {
    int e = blockIdx.x * blockDim.x + threadIdx.x;
    if (e < E) atomicAdd(&deg[row[e]], 1.0f);
}

__global__ void gcn_rsqrt_kernel(float* __restrict__ deg, int N) {
    int i = blockIdx.x * blockDim.x + threadIdx.x;
    if (i < N) {
        float d = deg[i];
        deg[i] = (d > 0.0f) ? rsqrtf(d) : 0.0f;
    }
}

__global__ void gcn_scatter_kernel(const int* __restrict__ row,
                                   const int* __restrict__ col,
                                   const float* __restrict__ feat,
                                   const float* __restrict__ dinv,
                                   float* __restrict__ out, int E) {
    long long tid = (long long)blockIdx.x * blockDim.x + threadIdx.x;
    int e = (int)(tid >> 6);
    int d = (int)(tid & 63);
    if (e < E) {
        int r = row[e];
        int c = col[e];
        float v = dinv[r] * dinv[c];
        float x = feat[(long long)c * DFEAT + d];
        atomicAdd(&out[(long long)r * DFEAT + d], v * x);
    }
}

extern "C" void kernel_launch(void* const* d_in, const int* in_sizes, int n_in,
                              void* d_out, int out_size, void* d_ws, size_t ws_size,
                              hipStream_t stream) {
    const float* feat = (const float*)d_in[0];
    const int*   row  = (const int*)d_in[1];
    const int*   col  = (const int*)d_in[2];
    float* out = (float*)d_out;

    int N = in_sizes[0] / DFEAT;   // 100000
    int E = in_sizes[1];           // 1600000
    int NB = (N + SCAN_B - 1) / SCAN_B;
    int K  = (N + RPB - 1) / RPB;  // buckets

    size_t need = (size_t)(5 * N + 2 + 2 * NB + 2 + KMAX) * 4 + (size_t)E * 4;
    if (ws_size < need) {
        float* deg = (float*)d_ws;
        hipMemsetAsync(out, 0, (size_t)out_size * sizeof(float), stream);
        hipMemsetAsync(deg, 0, (size_t)N * sizeof(float), stream);
        gcn_deg_kernel<<<(E + 255) / 256, 256, 0, stream>>>(row, deg, E);
        gcn_rsqrt_kernel<<<(N + 255) / 256, 256, 0, stream>>>(deg, N);
        long long total = (long long)E * DFEAT;
        gcn_scatter_kernel<<<(int)((total + 255) / 256), 256, 0, stream>>>(
            row, col, feat, deg, out, E);
        return;
    }

    unsigned* cnt        = (unsigned*)d_ws;         // N
    unsigned* part       = cnt + N;                 // N
    unsigned* row_ptr    = part + N;                // N+1
    unsigned* fill       = row_ptr + N + 1;         // N (fallback only)
    unsigned* bsum       = fill + N;                // NB
    unsigned* bscan      = bsum + NB;               // NB
    unsigned* bscratch   = bscan + NB;              // 1
    unsigned* bucket_fill= bscratch + 1;            // KMAX
    float*    dinv       = (float*)(bucket_fill + KMAX); // N
    int*      col_sorted = (int*)(dinv + N);        // E
    int*      pair_buf   = (int*)d_out;             // E (scratch in d_out,
                                                    // consumed before gather)

    hipMemsetAsync(cnt, 0, (size_t)N * sizeof(unsigned), stream);
    hipMemsetAsync(bucket_fill, 0, (size_t)KMAX * sizeof(unsigned), stream);

    int histThreads = (E + 3) / 4;
    gcn_hist_kernel<<<(histThreads + 255) / 256, 256, 0, stream>>>(row, cnt, E);
    gcn_scan_block_kernel<<<NB, SCAN_B, 0, stream>>>(cnt, part, bsum, N);
    gcn_scan_block_kernel<<<1, SCAN_B, 0, stream>>>(bsum, bscan, bscratch, NB);
    gcn_scan_fixup_kernel<<<(N + 255) / 256, 256, 0, stream>>>(
        part, bscan, cnt, row_ptr, fill, dinv, N, E);

    if (K <= KMAX) {
        int binBlocks = (E + BIN_CHUNK - 1) / BIN_CHUNK;
        gcn_bin_kernel<<<binBlocks, 256, 0, stream>>>(row, col, row_ptr,
                                                      bucket_fill, pair_buf,
                                                      E, N, K);
        gcn_rank_kernel<<<K, 256, 0, stream>>>(pair_buf, row_ptr,
                                               col_sorted, N);
    } else {
        gcn_csr_scatter_kernel<<<(E + 255) / 256, 256, 0, stream>>>(
            row, col, fill, col_sorted, E);
    }

    gcn_gather_kernel<<<(N + 3) / 4, 256, 0, stream>>>(row_ptr, col_sorted,
                                                       feat, dinv, out, N);
}

// Round 5
// 128.486 us; speedup vs baseline: 3.4628x; 1.5468x over previous
//
#include <hip/hip_runtime.h>

#define DFEAT 64
#define SCAN_B 1024
#define RPB 128            // rows per bucket (power of 2)
#define RPB_SHIFT 7
#define KMAX 800           // bucket count limit (N <= 102400 for 17-bit col pack)
#define BIN_CHUNK 16384

// ---------- fused bucketed CSR-build path ----------

// Per-block LDS bucket histogram; ~K atomics per block instead of per edge.
__global__ __launch_bounds__(256) void gcn_bucket_hist_kernel(
    const int* __restrict__ row, unsigned* __restrict__ bucket_cnt,
    int E, int K) {
    __shared__ unsigned cnt[KMAX];
    int tid = threadIdx.x;
    long long e0 = (long long)blockIdx.x * BIN_CHUNK;
    int nE = min(BIN_CHUNK, (int)(E - e0));
    for (int k = tid; k < K; k += 256) cnt[k] = 0u;
    __syncthreads();
    int nE4 = nE & ~3;
    for (int i = tid * 4; i < nE4; i += 1024) {
        int4 r = *(const int4*)(row + e0 + i);
        atomicAdd(&cnt[r.x >> RPB_SHIFT], 1u);
        atomicAdd(&cnt[r.y >> RPB_SHIFT], 1u);
        atomicAdd(&cnt[r.z >> RPB_SHIFT], 1u);
        atomicAdd(&cnt[r.w >> RPB_SHIFT], 1u);
    }
    for (int i = nE4 + tid; i < nE; i += 256)
        atomicAdd(&cnt[row[e0 + i] >> RPB_SHIFT], 1u);
    __syncthreads();
    for (int k = tid; k < K; k += 256) {
        unsigned c = cnt[k];
        if (c) atomicAdd(&bucket_cnt[k], c);
    }
}

// Per-block exclusive scan (Hillis-Steele in LDS); block totals to bsum.
__global__ void gcn_scan_block_kernel(const unsigned* __restrict__ in,
                                      unsigned* __restrict__ part,
                                      unsigned* __restrict__ bsum, int n) {
    __shared__ unsigned tmp[SCAN_B];
    int tid = threadIdx.x;
    int i = blockIdx.x * SCAN_B + tid;
    unsigned v = (i < n) ? in[i] : 0u;
    tmp[tid] = v;
    __syncthreads();
    for (int off = 1; off < SCAN_B; off <<= 1) {
        unsigned t = (tid >= off) ? tmp[tid - off] : 0u;
        __syncthreads();
        tmp[tid] += t;
        __syncthreads();
    }
    if (i < n) part[i] = tmp[tid] - v;       // exclusive
    if (tid == 0) bsum[blockIdx.x] = tmp[SCAN_B - 1];
}

// Bucketed bin: LDS bucket counts, one global reservation per (block,bucket),
// packed 4B pair writes in contiguous per-block runs.
__global__ __launch_bounds__(256) void gcn_bin_kernel(
    const int* __restrict__ row, const int* __restrict__ col,
    const unsigned* __restrict__ bucket_ptr,
    unsigned* __restrict__ bucket_fill,   // K counters, zeroed
    int* __restrict__ pair_buf,           // E packed words (lives in d_out)
    int E, int K) {
    __shared__ unsigned cnt[KMAX];        // counts, then reused as rank
    __shared__ unsigned resbase[KMAX];
    int tid = threadIdx.x;
    long long e0 = (long long)blockIdx.x * BIN_CHUNK;
    int nE = min(BIN_CHUNK, (int)(E - e0));

    for (int k = tid; k < K; k += 256) cnt[k] = 0u;
    __syncthreads();
    for (int i = tid; i < nE; i += 256)
        atomicAdd(&cnt[row[e0 + i] >> RPB_SHIFT], 1u);
    __syncthreads();
    for (int k = tid; k < K; k += 256) {
        unsigned c = cnt[k];
        unsigned r = c ? atomicAdd(&bucket_fill[k], c) : 0u;
        resbase[k] = bucket_ptr[k] + r;
        cnt[k] = 0u;                       // reuse as write-rank counter
    }
    __syncthreads();
    for (int i = tid; i < nE; i += 256) {
        int r = row[e0 + i];
        int c = col[e0 + i];
        int k = r >> RPB_SHIFT;
        unsigned rank = atomicAdd(&cnt[k], 1u);
        pair_buf[resbase[k] + rank] = ((r & (RPB - 1)) << 17) | c;
    }
}

// One block per bucket: count per-row degrees, LDS-scan them, emit row_ptr
// slice + dinv, then rank edges into col_sorted (bucket-local writes).
__global__ __launch_bounds__(256) void gcn_rank_kernel(
    const int* __restrict__ pair_buf,
    const unsigned* __restrict__ bucket_ptr,
    unsigned* __restrict__ row_ptr,
    float* __restrict__ dinv,
    int* __restrict__ col_sorted, int N, int E, int K) {
    int k = blockIdx.x;
    int row0 = k << RPB_SHIFT;
    int rows_in = min(RPB, N - row0);
    __shared__ unsigned rcnt[RPB];
    __shared__ unsigned scan[RPB];
    __shared__ unsigned excl[RPB];
    __shared__ unsigned fillc[RPB];
    int tid = threadIdx.x;
    unsigned base = bucket_ptr[k];
    unsigned end  = (k == K - 1) ? (unsigned)E : bucket_ptr[k + 1];
    unsigned size = end - base;

    if (tid < RPB) { rcnt[tid] = 0u; fillc[tid] = 0u; }
    __syncthreads();
    for (unsigned i = tid; i < size; i += 256)
        atomicAdd(&rcnt[pair_buf[base + i] >> 17], 1u);
    __syncthreads();
    if (tid < RPB) scan[tid] = rcnt[tid];
    __syncthreads();
    for (int off = 1; off < RPB; off <<= 1) {
        unsigned t = (tid < RPB && tid >= off) ? scan[tid - off] : 0u;
        __syncthreads();
        if (tid < RPB) scan[tid] += t;
        __syncthreads();
    }
    if (tid < RPB) excl[tid] = scan[tid] - rcnt[tid];
    __syncthreads();
    if (tid < rows_in) {
        row_ptr[row0 + tid] = base + excl[tid];
        unsigned d = rcnt[tid];
        dinv[row0 + tid] = d ? rsqrtf((float)d) : 0.0f;
    }
    if (k == K - 1 && tid == 0) row_ptr[N] = (unsigned)E;
    for (unsigned i = tid; i < size; i += 256) {
        int w = pair_buf[base + i];
        int lr = w >> 17;
        unsigned rank = atomicAdd(&fillc[lr], 1u);
        col_sorted[base + excl[lr] + rank] = w & 0x1FFFF;
    }
}

// One wave per node; 4 edge-groups x 16 lanes, float4 feature loads,
// 2x unroll -> up to 8 feature rows in flight per wave.
__global__ __launch_bounds__(256) void gcn_gather_kernel(
    const unsigned* __restrict__ row_ptr,
    const int* __restrict__ col_sorted,
    const float* __restrict__ feat,
    const float* __restrict__ dinv,
    float* __restrict__ out, int N) {
    int node = blockIdx.x * 4 + (threadIdx.x >> 6);
    if (node >= N) return;
    int lane = threadIdx.x & 63;
    int grp = lane >> 4;
    int sub = lane & 15;

    unsigned s = row_ptr[node];
    unsigned epos = row_ptr[node + 1];

    float4 acc = make_float4(0.f, 0.f, 0.f, 0.f);
    unsigned j = s + grp;
    for (; j + 4 < epos; j += 8) {
        int c0 = col_sorted[j];
        int c1 = col_sorted[j + 4];
        float w0 = dinv[c0];
        float w1 = dinv[c1];
        float4 x0 = ((const float4*)(feat + (size_t)c0 * DFEAT))[sub];
        float4 x1 = ((const float4*)(feat + (size_t)c1 * DFEAT))[sub];
        acc.x += w0 * x0.x + w1 * x1.x;
        acc.y += w0 * x0.y + w1 * x1.y;
        acc.z += w0 * x0.z + w1 * x1.z;
        acc.w += w0 * x0.w + w1 * x1.w;
    }
    if (j < epos) {
        int c0 = col_sorted[j];
        float w0 = dinv[c0];
        float4 x0 = ((const float4*)(feat + (size_t)c0 * DFEAT))[sub];
        acc.x += w0 * x0.x;
        acc.y += w0 * x0.y;
        acc.z += w0 * x0.z;
        acc.w += w0 * x0.w;
    }
    acc.x += __shfl_xor(acc.x, 16, 64);
    acc.y += __shfl_xor(acc.y, 16, 64);
    acc.z += __shfl_xor(acc.z, 16, 64);
    acc.w += __shfl_xor(acc.w, 16, 64);
    acc.x += __shfl_xor(acc.x, 32, 64);
    acc.y += __shfl_xor(acc.y, 32, 64);
    acc.z += __shfl_xor(acc.z, 32, 64);
    acc.w += __shfl_xor(acc.w, 32, 64);

    if (grp == 0) {
        float w = dinv[node];
        float4 o = make_float4(w * acc.x, w * acc.y, w * acc.z, w * acc.w);
        ((float4*)(out + (size_t)node * DFEAT))[sub] = o;
    }
}

// ---------- fallback (round-1 atomic path) ----------

__global__ void gcn_deg_kernel(const int* __restrict__ row,
                               float* __restrict__ deg, int E) {
    int e = blockIdx.x * blockDim.x + threadIdx.x;
    if (e < E) atomicAdd(&deg[row[e]], 1.0f);
}

__global__ void gcn_rsqrt_kernel(float* __restrict__ deg, int N) {
    int i = blockIdx.x * blockDim.x + threadIdx.x;
    if (i < N) {
        float d = deg[i];
        deg[i] = (d > 0.0f) ? rsqrtf(d) : 0.0f;
    }
}

__global__ void gcn_scatter_kernel(const int* __restrict__ row,
                                   const int* __restrict__ col,
                                   const float* __restrict__ feat,
                                   const float* __restrict__ dinv,
                                   float* __restrict__ out, int E) {
    long long tid = (long long)blockIdx.x * blockDim.x + threadIdx.x;
    int e = (int)(tid >> 6);
    int d = (int)(tid & 63);
    if (e < E) {
        int r = row[e];
        int c = col[e];
        float v = dinv[r] * dinv[c];
        float x = feat[(long long)c * DFEAT + d];
        atomicAdd(&out[(long long)r * DFEAT + d], v * x);
    }
}

extern "C" void kernel_launch(void* const* d_in, const int* in_sizes, int n_in,
                              void* d_out, int out_size, void* d_ws, size_t ws_size,
                              hipStream_t stream) {
    const float* feat = (const float*)d_in[0];
    const int*   row  = (const int*)d_in[1];
    const int*   col  = (const int*)d_in[2];
    float* out = (float*)d_out;

    int N = in_sizes[0] / DFEAT;   // 100000
    int E = in_sizes[1];           // 1600000
    int K = (N + RPB - 1) / RPB;   // buckets

    // fused-path workspace: 3*KMAX+1 + (N+1) + N words + E words
    size_t need = (size_t)(3 * KMAX + 1 + 2 * N + 1) * 4 + (size_t)E * 4;
    bool pack_ok = (N <= (1 << 17)) && (K <= KMAX);
    if (!pack_ok || ws_size < need) {
        // fallback: atomic scatter path (correct for any N/E)
        float* deg = (float*)d_ws;
        hipMemsetAsync(out, 0, (size_t)out_size * sizeof(float), stream);
        hipMemsetAsync(deg, 0, (size_t)N * sizeof(float), stream);
        gcn_deg_kernel<<<(E + 255) / 256, 256, 0, stream>>>(row, deg, E);
        gcn_rsqrt_kernel<<<(N + 255) / 256, 256, 0, stream>>>(deg, N);
        long long total = (long long)E * DFEAT;
        gcn_scatter_kernel<<<(int)((total + 255) / 256), 256, 0, stream>>>(
            row, col, feat, deg, out, E);
        return;
    }

    unsigned* bucket_cnt  = (unsigned*)d_ws;             // KMAX
    unsigned* bucket_ptr  = bucket_cnt + KMAX;           // KMAX
    unsigned* bucket_fill = bucket_ptr + KMAX;           // KMAX
    unsigned* bscratch    = bucket_fill + KMAX;          // 1
    unsigned* row_ptr     = bscratch + 1;                // N+1
    float*    dinv        = (float*)(row_ptr + N + 1);   // N
    int*      col_sorted  = (int*)(dinv + N);            // E
    int*      pair_buf    = (int*)d_out;                 // E (scratch in d_out,
                                                         // consumed before gather)

    hipMemsetAsync(bucket_cnt, 0, (size_t)K * sizeof(unsigned), stream);
    hipMemsetAsync(bucket_fill, 0, (size_t)K * sizeof(unsigned), stream);

    int binBlocks = (E + BIN_CHUNK - 1) / BIN_CHUNK;
    gcn_bucket_hist_kernel<<<binBlocks, 256, 0, stream>>>(row, bucket_cnt, E, K);
    gcn_scan_block_kernel<<<1, SCAN_B, 0, stream>>>(bucket_cnt, bucket_ptr,
                                                    bscratch, K);
    gcn_bin_kernel<<<binBlocks, 256, 0, stream>>>(row, col, bucket_ptr,
                                                  bucket_fill, pair_buf, E, K);
    gcn_rank_kernel<<<K, 256, 0, stream>>>(pair_buf, bucket_ptr, row_ptr,
                                           dinv, col_sorted, N, E, K);
    gcn_gather_kernel<<<(N + 3) / 4, 256, 0, stream>>>(row_ptr, col_sorted,
                                                       feat, dinv, out, N);
}